// Round 1
// baseline (807.710 us; speedup 1.0000x reference)
//
#include <hip/hip_runtime.h>
#include <hip/hip_bf16.h>

// Problem constants
#define H_IN   128
#define W_IN   128
#define B_SZ   64
#define CONV_O 126            // (128-2)
#define K_DIM  15876          // 126*126
#define N_TRI  8256           // 128*129/2
#define N_OUT  128
#define BK     32
#define BN     32
#define NSTEPS 497            // ceil(15876/32)
#define HPAD   15904          // 497*32, zero-padded h
#define KSPLIT 8

typedef short  short8  __attribute__((ext_vector_type(8)));
typedef float  floatx4 __attribute__((ext_vector_type(4)));

__device__ inline short f2bf(float f) {
    union { __hip_bfloat16 h; short s; } u;
    u.h = __float2bfloat16(f);
    return u.s;
}

// ---------------------------------------------------------------------------
// Kernel 1: fused conv1(3x3,1->4)+bias+relu -> conv2(1x1,4->1)+bias, output
// h[b][p] as bf16, zero-padded to HPAD columns.
// ---------------------------------------------------------------------------
__global__ __launch_bounds__(256) void conv_kernel(
    const float* __restrict__ x,    // [64][1][128][128]
    const float* __restrict__ w1,   // [4][1][3][3]
    const float* __restrict__ b1,   // [4]
    const float* __restrict__ w2,   // [1][4][1][1]
    const float* __restrict__ b2,   // [1]
    unsigned short* __restrict__ h) // [64][HPAD] bf16
{
    int t = blockIdx.x * 256 + threadIdx.x;      // < 64*HPAD
    int b = t / HPAD;
    int p = t - b * HPAD;
    float val = 0.f;
    if (p < K_DIM) {
        int oy = p / CONV_O;
        int ox = p - oy * CONV_O;
        const float* xb = x + b * (H_IN * W_IN) + oy * W_IN + ox;
        float xin[9];
#pragma unroll
        for (int dy = 0; dy < 3; ++dy)
#pragma unroll
            for (int dx = 0; dx < 3; ++dx)
                xin[dy * 3 + dx] = xb[dy * W_IN + dx];
        float acc = b2[0];
#pragma unroll
        for (int c = 0; c < 4; ++c) {
            float s = b1[c];
#pragma unroll
            for (int q = 0; q < 9; ++q) s = fmaf(w1[c * 9 + q], xin[q], s);
            s = fmaxf(s, 0.f);
            acc = fmaf(w2[c], s, acc);
        }
        val = acc;
    }
    h[t] = (unsigned short)f2bf(val);
}

// ---------------------------------------------------------------------------
// Kernel 2: v[64][8256] += h[64][K] @ out_w[8256][K]^T  (bf16 MFMA, K-split,
// fp32 atomic accumulate). Block: 256 thr = 4 waves; tile M=64 x N=32 x K=32.
// ---------------------------------------------------------------------------
__global__ __launch_bounds__(256, 4) void gemm_kernel(
    const unsigned short* __restrict__ h,  // [64][HPAD] bf16 (zero padded)
    const float* __restrict__ w,           // [N_TRI][K_DIM] fp32
    float* __restrict__ v)                 // [64][N_TRI] fp32 (pre-zeroed)
{
    __shared__ __align__(16) short As[64 * 40];  // [64 m][32 k] stride 40
    __shared__ __align__(16) short Bs[32 * 40];  // [32 n][32 k] stride 40

    const int n0    = blockIdx.x * BN;
    const int split = blockIdx.y;
    const int s0 = (NSTEPS * split) / KSPLIT;
    const int s1 = (NSTEPS * (split + 1)) / KSPLIT;

    const int t    = threadIdx.x;
    const int lane = t & 63;
    const int wv   = t >> 6;
    const int quad = lane >> 4;
    const int l16  = lane & 15;

    // staging assignment
    const int arow = t >> 2, acol = (t & 3) * 8;  // 8 bf16 (16B) per thread
    const int brow = t >> 3, bcol = (t & 7) * 4;  // 4 fp32 (16B) per thread

    const int mh = (wv >> 1) * 32;   // wave's m-half
    const int nw = (wv & 1) * 16;    // wave's n-subtile

    // LDS fragment offsets (in shorts)
    const int aoff0 = (mh + l16) * 40 + quad * 8;
    const int aoff1 = (mh + 16 + l16) * 40 + quad * 8;
    const int boff  = (nw + l16) * 40 + quad * 8;

    floatx4 acc0 = {0.f, 0.f, 0.f, 0.f};
    floatx4 acc1 = {0.f, 0.f, 0.f, 0.f};

    for (int s = s0; s < s1; ++s) {
        const int k0 = s * BK;

        __syncthreads();
        // ---- stage A (h, already bf16): 64x32 tile, coalesced 16B loads
        {
            int4 av = *(const int4*)(h + (size_t)arow * HPAD + k0 + acol);
            *(int4*)(As + arow * 40 + acol) = av;
        }
        // ---- stage B (out_w fp32 -> bf16): 32x32 tile
        {
            const float* wp = w + (size_t)(n0 + brow) * K_DIM + k0 + bcol;
            float4 bv;
            if (k0 + BK <= K_DIM) {
                bv = *(const float4*)wp;
            } else {
                bv.x = (k0 + bcol + 0 < K_DIM) ? wp[0] : 0.f;
                bv.y = (k0 + bcol + 1 < K_DIM) ? wp[1] : 0.f;
                bv.z = (k0 + bcol + 2 < K_DIM) ? wp[2] : 0.f;
                bv.w = (k0 + bcol + 3 < K_DIM) ? wp[3] : 0.f;
            }
            short4 bs = make_short4(f2bf(bv.x), f2bf(bv.y), f2bf(bv.z), f2bf(bv.w));
            *(short4*)(Bs + brow * 40 + bcol) = bs;
        }
        __syncthreads();

        // ---- MFMA: two 16x16 m-tiles x one 16-wide n-tile per wave
        short8 af0 = *(const short8*)(As + aoff0);
        short8 af1 = *(const short8*)(As + aoff1);
        short8 bf  = *(const short8*)(Bs + boff);
        acc0 = __builtin_amdgcn_mfma_f32_16x16x32_bf16(af0, bf, acc0, 0, 0, 0);
        acc1 = __builtin_amdgcn_mfma_f32_16x16x32_bf16(af1, bf, acc1, 0, 0, 0);
    }

    // ---- epilogue: atomic accumulate partial sums
    const int n = n0 + nw + l16;
#pragma unroll
    for (int r = 0; r < 4; ++r) {
        int m0 = mh + quad * 4 + r;
        atomicAdd(&v[(size_t)m0 * N_TRI + n], acc0[r]);
        atomicAdd(&v[(size_t)(m0 + 16) * N_TRI + n], acc1[r]);
    }
}

// ---------------------------------------------------------------------------
// Kernel 3: symmetric triu scatter + bias: y[b][i][j] = v[b][tri(min,max)] + ob
// ---------------------------------------------------------------------------
__global__ __launch_bounds__(256) void scatter_kernel(
    const float* __restrict__ v,      // [64][N_TRI]
    const float* __restrict__ out_b,  // [N_TRI]
    float* __restrict__ y)            // [64][1][128][128]
{
    int t = blockIdx.x * 256 + threadIdx.x;  // < 64*16384
    int b  = t >> 14;
    int ij = t & 16383;
    int i = ij >> 7, j = ij & 127;
    int ii = min(i, j), jj = max(i, j);
    int tri = ii * N_OUT - ((ii * (ii - 1)) >> 1) + (jj - ii);
    y[t] = v[(size_t)b * N_TRI + tri] + out_b[tri];
}

// ---------------------------------------------------------------------------
extern "C" void kernel_launch(void* const* d_in, const int* in_sizes, int n_in,
                              void* d_out, int out_size, void* d_ws, size_t ws_size,
                              hipStream_t stream) {
    const float* x   = (const float*)d_in[0];
    const float* c1w = (const float*)d_in[1];
    const float* c1b = (const float*)d_in[2];
    const float* c2w = (const float*)d_in[3];
    const float* c2b = (const float*)d_in[4];
    const float* ow  = (const float*)d_in[5];
    const float* ob  = (const float*)d_in[6];
    float* y = (float*)d_out;

    // workspace layout: h bf16 [64][HPAD] | v fp32 [64][N_TRI]
    unsigned short* h = (unsigned short*)d_ws;
    float* v = (float*)((char*)d_ws + (size_t)B_SZ * HPAD * 2);  // 2,035,712 B (16B aligned)

    hipMemsetAsync(v, 0, (size_t)B_SZ * N_TRI * sizeof(float), stream);

    conv_kernel<<<(B_SZ * HPAD) / 256, 256, 0, stream>>>(x, c1w, c1b, c2w, c2b, h);
    gemm_kernel<<<dim3(N_TRI / BN, KSPLIT), 256, 0, stream>>>(h, ow, v);
    scatter_kernel<<<(B_SZ * N_OUT * N_OUT) / 256, 256, 0, stream>>>(v, ob, y);
}

// Round 2
// 733.571 us; speedup vs baseline: 1.1011x; 1.1011x over previous
//
#include <hip/hip_runtime.h>
#include <hip/hip_bf16.h>

// Problem constants
#define H_IN   128
#define W_IN   128
#define B_SZ   64
#define CONV_O 126            // (128-2)
#define K_DIM  15876          // 126*126
#define N_TRI  8256           // 128*129/2
#define N_OUT  128
#define BK     32
#define BN     64
#define NSTEPS 497            // ceil(15876/32)
#define K8     1988           // NSTEPS*4 groups of 8 k-elements (zero-padded)
#define KSPLIT 16

typedef short  short8  __attribute__((ext_vector_type(8)));
typedef float  floatx4 __attribute__((ext_vector_type(4)));

__device__ inline short f2bf(float f) {
    union { __hip_bfloat16 h; short s; } u;
    u.h = __float2bfloat16(f);
    return u.s;
}

// ---------------------------------------------------------------------------
// Kernel 1: fused conv1(3x3,1->4)+bias+relu -> conv2(1x1,4->1)+bias.
// Output h pre-swizzled into MFMA A-fragment order:
//   hsw[k8][m][j]  (k8 = p>>3, j = p&7, m = batch), zero-padded for p>=K_DIM.
// This lets the GEMM load A fragments directly from global (L2-hot, 2 MB)
// with one coalesced 16B load per fragment — no A staging through LDS.
// ---------------------------------------------------------------------------
__global__ __launch_bounds__(256) void conv_kernel(
    const float* __restrict__ x,    // [64][1][128][128]
    const float* __restrict__ w1,   // [4][1][3][3]
    const float* __restrict__ b1,   // [4]
    const float* __restrict__ w2,   // [1][4][1][1]
    const float* __restrict__ b2,   // [1]
    unsigned short* __restrict__ hsw) // [K8][64][8] bf16
{
    int t = blockIdx.x * 256 + threadIdx.x;      // < K8*64*8
    int j  = t & 7;
    int m  = (t >> 3) & 63;
    int k8 = t >> 9;
    int p  = k8 * 8 + j;
    float val = 0.f;
    if (p < K_DIM) {
        int oy = p / CONV_O;
        int ox = p - oy * CONV_O;
        const float* xb = x + m * (H_IN * W_IN) + oy * W_IN + ox;
        float xin[9];
#pragma unroll
        for (int dy = 0; dy < 3; ++dy)
#pragma unroll
            for (int dx = 0; dx < 3; ++dx)
                xin[dy * 3 + dx] = xb[dy * W_IN + dx];
        float acc = b2[0];
#pragma unroll
        for (int c = 0; c < 4; ++c) {
            float s = b1[c];
#pragma unroll
            for (int q = 0; q < 9; ++q) s = fmaf(w1[c * 9 + q], xin[q], s);
            s = fmaxf(s, 0.f);
            acc = fmaf(w2[c], s, acc);
        }
        val = acc;
    }
    hsw[t] = (unsigned short)f2bf(val);
}

// ---------------------------------------------------------------------------
// Kernel 2: v[64][8256] += h[64][K] @ out_w[8256][K]^T
// Block: 256 thr = 4 waves (2x2), tile M=64 x N=64 x K=32, wave tile 32x32.
// A fragments: direct global loads from swizzled hsw (L2-resident, 2 MB).
// B: coalesced fp32 load -> bf16 convert -> LDS (stride 40: 2-way alias, free).
// K split 16 ways; fp32 atomicAdd into pre-zeroed v.
// ---------------------------------------------------------------------------
__global__ __launch_bounds__(256, 4) void gemm_kernel(
    const unsigned short* __restrict__ hsw, // [K8][64][8] bf16
    const float* __restrict__ w,            // [N_TRI][K_DIM] fp32
    float* __restrict__ v)                  // [64][N_TRI] fp32 (pre-zeroed)
{
    __shared__ __align__(16) short Bs[64 * 40];  // [64 n][32 k] stride 40

    const int n0    = blockIdx.x * BN;
    const int split = blockIdx.y;
    const int s0 = (NSTEPS * split) / KSPLIT;
    const int s1 = (NSTEPS * (split + 1)) / KSPLIT;

    const int t    = threadIdx.x;
    const int lane = t & 63;
    const int wv   = t >> 6;
    const int quad = lane >> 4;
    const int l16  = lane & 15;

    const int mh = (wv >> 1) * 32;   // wave's m-origin (0 or 32)
    const int nq = (wv & 1) * 32;    // wave's n-origin within block (0 or 32)

    // B staging: 4 threads per row, 8 consecutive k each (32B contiguous)
    const int brow = t >> 2;
    const int bk   = (t & 3) * 8;

    // LDS fragment offsets (shorts)
    const int boff0 = (nq + l16) * 40 + quad * 8;
    const int boff1 = (nq + 16 + l16) * 40 + quad * 8;

    floatx4 acc00 = {0.f,0.f,0.f,0.f}, acc01 = {0.f,0.f,0.f,0.f};
    floatx4 acc10 = {0.f,0.f,0.f,0.f}, acc11 = {0.f,0.f,0.f,0.f};

    for (int s = s0; s < s1; ++s) {
        const int k0 = s * BK;

        // ---- B global load (issue before sync so it flies during the wait)
        const float* wp = w + (size_t)(n0 + brow) * K_DIM + k0 + bk;
        float bv[8];
        if (k0 + BK <= K_DIM) {
            float4 x0 = *(const float4*)wp;
            float4 x1 = *(const float4*)(wp + 4);
            bv[0]=x0.x; bv[1]=x0.y; bv[2]=x0.z; bv[3]=x0.w;
            bv[4]=x1.x; bv[5]=x1.y; bv[6]=x1.z; bv[7]=x1.w;
        } else {
#pragma unroll
            for (int q = 0; q < 8; ++q)
                bv[q] = (k0 + bk + q < K_DIM) ? wp[q] : 0.f;
        }
        short8 bs;
#pragma unroll
        for (int q = 0; q < 8; ++q) bs[q] = f2bf(bv[q]);

        __syncthreads();               // prior iter's Bs reads done
        *(short8*)(Bs + brow * 40 + bk) = bs;
        __syncthreads();               // Bs ready

        // ---- A fragments straight from global (L2)
        const unsigned short* ap = hsw + (size_t)(s * 4 + quad) * (64 * 8);
        short8 a0 = *(const short8*)(ap + (mh + l16) * 8);
        short8 a1 = *(const short8*)(ap + (mh + 16 + l16) * 8);
        short8 b0 = *(const short8*)(Bs + boff0);
        short8 b1 = *(const short8*)(Bs + boff1);

        acc00 = __builtin_amdgcn_mfma_f32_16x16x32_bf16(a0, b0, acc00, 0, 0, 0);
        acc01 = __builtin_amdgcn_mfma_f32_16x16x32_bf16(a0, b1, acc01, 0, 0, 0);
        acc10 = __builtin_amdgcn_mfma_f32_16x16x32_bf16(a1, b0, acc10, 0, 0, 0);
        acc11 = __builtin_amdgcn_mfma_f32_16x16x32_bf16(a1, b1, acc11, 0, 0, 0);
    }

    // ---- epilogue: atomic accumulate partial sums
    const int nc = n0 + nq + l16;
#pragma unroll
    for (int r = 0; r < 4; ++r) {
        int m = mh + quad * 4 + r;
        atomicAdd(&v[(size_t)m * N_TRI + nc],              acc00[r]);
        atomicAdd(&v[(size_t)m * N_TRI + nc + 16],         acc01[r]);
        atomicAdd(&v[(size_t)(m + 16) * N_TRI + nc],       acc10[r]);
        atomicAdd(&v[(size_t)(m + 16) * N_TRI + nc + 16],  acc11[r]);
    }
}

// ---------------------------------------------------------------------------
// Kernel 3: symmetric triu scatter + bias: y[b][i][j] = v[b][tri(min,max)] + ob
// ---------------------------------------------------------------------------
__global__ __launch_bounds__(256) void scatter_kernel(
    const float* __restrict__ v,      // [64][N_TRI]
    const float* __restrict__ out_b,  // [N_TRI]
    float* __restrict__ y)            // [64][1][128][128]
{
    int t = blockIdx.x * 256 + threadIdx.x;  // < 64*16384
    int b  = t >> 14;
    int ij = t & 16383;
    int i = ij >> 7, j = ij & 127;
    int ii = min(i, j), jj = max(i, j);
    int tri = ii * N_OUT - ((ii * (ii - 1)) >> 1) + (jj - ii);
    y[t] = v[(size_t)b * N_TRI + tri] + out_b[tri];
}

// ---------------------------------------------------------------------------
extern "C" void kernel_launch(void* const* d_in, const int* in_sizes, int n_in,
                              void* d_out, int out_size, void* d_ws, size_t ws_size,
                              hipStream_t stream) {
    const float* x   = (const float*)d_in[0];
    const float* c1w = (const float*)d_in[1];
    const float* c1b = (const float*)d_in[2];
    const float* c2w = (const float*)d_in[3];
    const float* c2b = (const float*)d_in[4];
    const float* ow  = (const float*)d_in[5];
    const float* ob  = (const float*)d_in[6];
    float* y = (float*)d_out;

    // workspace layout: hsw bf16 [K8][64][8] | v fp32 [64][N_TRI]
    unsigned short* hsw = (unsigned short*)d_ws;
    float* v = (float*)((char*)d_ws + (size_t)K8 * 64 * 8 * 2);  // 2,035,712 B

    hipMemsetAsync(v, 0, (size_t)B_SZ * N_TRI * sizeof(float), stream);

    conv_kernel<<<(K8 * 64 * 8) / 256, 256, 0, stream>>>(x, c1w, c1b, c2w, c2b, hsw);
    gemm_kernel<<<dim3(N_TRI / BN, KSPLIT), 256, 0, stream>>>(hsw, ow, v);
    scatter_kernel<<<(B_SZ * N_OUT * N_OUT) / 256, 256, 0, stream>>>(v, ob, y);
}